// Round 2
// baseline (750.044 us; speedup 1.0000x reference)
//
#include <hip/hip_runtime.h>

// in[0]=x [B,TF,T], in[1]=gene_ids [T], in[2]=w_sub [TF,T], in[3]=b_sub [G],
// in[4]=edge_index [2,2E], in[5]=w_conv [1,2], in[6]=b_conv [2],
// in[7]=w_out [2G,3], in[8]=b_out [3]
// d_out = x_cat [B,G] ++ g [B,2G] ++ out [B,3]  (float32)

// ---------------- Stage 1: per-gene subnet dot + segment scatter ----------------
// 4 batches per thread: w_sub tile is read once per 4 batches instead of per batch.
// z[b,t] = sum_tf x[b,tf,t]*w_sub[tf,t];  acc[b, gene_ids[t]] += z[b,t]
__global__ void k_subnet4(const float* __restrict__ x, const float* __restrict__ w_sub,
                          const int* __restrict__ gene_ids, float* __restrict__ acc,
                          int TF, int T, int G, int B) {
    int t = (blockIdx.x * blockDim.x + threadIdx.x) * 4;
    if (t >= T) return;
    int b0 = blockIdx.y * 4;
    int nb = B - b0; if (nb > 4) nb = 4;
    const size_t planeT = (size_t)TF * T;

    if (t + 3 < T && (T % 4) == 0) {
        const size_t strideV = (size_t)T / 4;
        const float4* wp = (const float4*)(w_sub + t);
        const float4* xp0 = (const float4*)(x + (size_t)(b0 + 0) * planeT + t);
        const float4* xp1 = (const float4*)(x + (size_t)(b0 + 1) * planeT + t);
        const float4* xp2 = (const float4*)(x + (size_t)(b0 + 2) * planeT + t);
        const float4* xp3 = (const float4*)(x + (size_t)(b0 + 3) * planeT + t);

        float4 a0 = make_float4(0.f,0.f,0.f,0.f);
        float4 a1 = a0, a2 = a0, a3 = a0;

        if (nb == 4) {
            #pragma unroll 4
            for (int tf = 0; tf < TF; ++tf) {
                size_t off = (size_t)tf * strideV;
                float4 wv = wp[off];
                float4 x0 = xp0[off];
                float4 x1 = xp1[off];
                float4 x2 = xp2[off];
                float4 x3 = xp3[off];
                a0.x += x0.x*wv.x; a0.y += x0.y*wv.y; a0.z += x0.z*wv.z; a0.w += x0.w*wv.w;
                a1.x += x1.x*wv.x; a1.y += x1.y*wv.y; a1.z += x1.z*wv.z; a1.w += x1.w*wv.w;
                a2.x += x2.x*wv.x; a2.y += x2.y*wv.y; a2.z += x2.z*wv.z; a2.w += x2.w*wv.w;
                a3.x += x3.x*wv.x; a3.y += x3.y*wv.y; a3.z += x3.z*wv.z; a3.w += x3.w*wv.w;
            }
        } else {
            for (int tf = 0; tf < TF; ++tf) {
                size_t off = (size_t)tf * strideV;
                float4 wv = wp[off];
                if (nb > 0) { float4 xv = xp0[off]; a0.x += xv.x*wv.x; a0.y += xv.y*wv.y; a0.z += xv.z*wv.z; a0.w += xv.w*wv.w; }
                if (nb > 1) { float4 xv = xp1[off]; a1.x += xv.x*wv.x; a1.y += xv.y*wv.y; a1.z += xv.z*wv.z; a1.w += xv.w*wv.w; }
                if (nb > 2) { float4 xv = xp2[off]; a2.x += xv.x*wv.x; a2.y += xv.y*wv.y; a2.z += xv.z*wv.z; a2.w += xv.w*wv.w; }
            }
        }

        int g0 = gene_ids[t], g1 = gene_ids[t+1], g2 = gene_ids[t+2], g3 = gene_ids[t+3];
        float4 as[4] = {a0, a1, a2, a3};
        for (int bb = 0; bb < nb; ++bb) {
            float* base = acc + (size_t)(b0 + bb) * G;
            float4 a = as[bb];
            float v = a.x; int cg = g0;
            if (g1 == cg) v += a.y; else { atomicAdd(base + cg, v); cg = g1; v = a.y; }
            if (g2 == cg) v += a.z; else { atomicAdd(base + cg, v); cg = g2; v = a.z; }
            if (g3 == cg) v += a.w; else { atomicAdd(base + cg, v); cg = g3; v = a.w; }
            atomicAdd(base + cg, v);
        }
    } else {
        // scalar tail (not taken for T % 4 == 0, kept for generality)
        for (int bb = 0; bb < nb; ++bb) {
            int b = b0 + bb;
            for (int tt = t; tt < T && tt < t + 4; ++tt) {
                float a = 0.f;
                for (int tf = 0; tf < TF; ++tf)
                    a += x[(size_t)b * planeT + (size_t)tf * T + tt] * w_sub[(size_t)tf * T + tt];
                atomicAdd(acc + (size_t)b * G + gene_ids[tt], a);
            }
        }
    }
}

// ---------------- Stage 2: x_cat = relu(acc + b_sub) ----------------
__global__ void k_xcat(const float* __restrict__ acc, const float* __restrict__ b_sub,
                       float* __restrict__ xcat, int BG, int G) {
    int i = blockIdx.x * blockDim.x + threadIdx.x;
    if (i >= BG) return;
    int g = i % G;
    float v = acc[i] + b_sub[g];
    xcat[i] = v > 0.f ? v : 0.f;
}

// ---------------- Stage 3: degree count over dst row ----------------
__global__ void k_deg(const int* __restrict__ ei, float* __restrict__ deg, int E2) {
    int e = blockIdx.x * blockDim.x + threadIdx.x;
    if (e < E2) atomicAdd(&deg[ei[E2 + e]], 1.0f);
}

// ---------------- Stage 4: deg -> dinv in place ----------------
__global__ void k_dinv(float* __restrict__ deg, int G) {
    int g = blockIdx.x * blockDim.x + threadIdx.x;
    if (g < G) {
        float d = deg[g];
        deg[g] = (d > 0.f) ? (1.0f / sqrtf(fmaxf(d, 1.0f))) : 0.f;
    }
}

// ---------------- Stage 5: edge scatter s[b,dst] += xcat[b,src]*norm ----------------
__global__ void k_scatter(const float* __restrict__ xcat, const int* __restrict__ ei,
                          const float* __restrict__ dinv, float* __restrict__ s,
                          int G, int E2, int total) {
    int idx = blockIdx.x * blockDim.x + threadIdx.x;
    if (idx >= total) return;
    int b = idx / E2;
    int e = idx - b * E2;
    int src = ei[e], dst = ei[E2 + e];
    float norm = dinv[src] * dinv[dst];
    atomicAdd(&s[(size_t)b * G + dst], xcat[(size_t)b * G + src] * norm);
}

// ---------------- Stage 6: g = relu(w_conv*s + b_conv) ----------------
__global__ void k_gfin(const float* __restrict__ s, const float* __restrict__ w_conv,
                       const float* __restrict__ b_conv, float* __restrict__ gout, int BG) {
    int i = blockIdx.x * blockDim.x + threadIdx.x;   // i = b*G + n
    if (i >= BG) return;
    float sv = s[i];
    float g0 = sv * w_conv[0] + b_conv[0];
    float g1 = sv * w_conv[1] + b_conv[1];
    gout[2 * (size_t)i + 0] = g0 > 0.f ? g0 : 0.f;   // b*2G + 2n + f == 2*i + f
    gout[2 * (size_t)i + 1] = g1 > 0.f ? g1 : 0.f;
}

// ---------------- Stage 7: out = g @ w_out + b_out ----------------
__global__ void k_out(const float* __restrict__ gmat, const float* __restrict__ w_out,
                      const float* __restrict__ b_out, float* __restrict__ out, int G2) {
    int b = blockIdx.x;
    float a0 = 0.f, a1 = 0.f, a2 = 0.f;
    for (int i = threadIdx.x; i < G2; i += blockDim.x) {
        float gv = gmat[(size_t)b * G2 + i];
        a0 += gv * w_out[3 * i + 0];
        a1 += gv * w_out[3 * i + 1];
        a2 += gv * w_out[3 * i + 2];
    }
    __shared__ float red[3][256];
    red[0][threadIdx.x] = a0; red[1][threadIdx.x] = a1; red[2][threadIdx.x] = a2;
    __syncthreads();
    for (int s = blockDim.x / 2; s > 0; s >>= 1) {
        if ((int)threadIdx.x < s) {
            red[0][threadIdx.x] += red[0][threadIdx.x + s];
            red[1][threadIdx.x] += red[1][threadIdx.x + s];
            red[2][threadIdx.x] += red[2][threadIdx.x + s];
        }
        __syncthreads();
    }
    if (threadIdx.x == 0) {
        out[b * 3 + 0] = red[0][0] + b_out[0];
        out[b * 3 + 1] = red[1][0] + b_out[1];
        out[b * 3 + 2] = red[2][0] + b_out[2];
    }
}

extern "C" void kernel_launch(void* const* d_in, const int* in_sizes, int n_in,
                              void* d_out, int out_size, void* d_ws, size_t ws_size,
                              hipStream_t stream) {
    const float* x        = (const float*)d_in[0];
    const int*   gene_ids = (const int*)d_in[1];
    const float* w_sub    = (const float*)d_in[2];
    const float* b_sub    = (const float*)d_in[3];
    const int*   ei       = (const int*)d_in[4];
    const float* w_conv   = (const float*)d_in[5];
    const float* b_conv   = (const float*)d_in[6];
    const float* w_out    = (const float*)d_in[7];
    const float* b_out    = (const float*)d_in[8];

    const int G  = in_sizes[3];
    const int T  = in_sizes[1];
    const int TF = in_sizes[2] / T;
    const int B  = in_sizes[0] / (TF * T);
    const int E2 = in_sizes[4] / 2;     // 2E
    const int BG = B * G;
    const int G2 = 2 * G;

    // workspace layout (floats): acc[BG] | deg/dinv[G] | s[BG]
    float* acc = (float*)d_ws;
    float* deg = acc + BG;
    float* s   = deg + G;
    size_t zero_bytes = (size_t)(BG + G + BG) * sizeof(float);
    hipMemsetAsync(d_ws, 0, zero_bytes, stream);

    float* out_xcat = (float*)d_out;          // [B, G]
    float* out_g    = out_xcat + BG;          // [B, 2G]
    float* out_fin  = out_g + (size_t)B * G2; // [B, 3]

    // Stage 1: 4 batches per thread (cuts w_sub re-reads 4x)
    {
        int tthreads = (T + 3) / 4;
        dim3 grid((tthreads + 255) / 256, (B + 3) / 4);
        k_subnet4<<<grid, 256, 0, stream>>>(x, w_sub, gene_ids, acc, TF, T, G, B);
    }
    // Stage 2
    k_xcat<<<(BG + 255) / 256, 256, 0, stream>>>(acc, b_sub, out_xcat, BG, G);
    // Stage 3
    k_deg<<<(E2 + 255) / 256, 256, 0, stream>>>(ei, deg, E2);
    // Stage 4
    k_dinv<<<(G + 255) / 256, 256, 0, stream>>>(deg, G);
    // Stage 5
    {
        int total = B * E2;
        k_scatter<<<(total + 255) / 256, 256, 0, stream>>>(out_xcat, ei, deg, s, G, E2, total);
    }
    // Stage 6
    k_gfin<<<(BG + 255) / 256, 256, 0, stream>>>(s, w_conv, b_conv, out_g, BG);
    // Stage 7
    k_out<<<B, 256, 0, stream>>>(out_g, w_out, b_out, out_fin, G2);
}